// Round 3
// baseline (724.716 us; speedup 1.0000x reference)
//
#include <hip/hip_runtime.h>
#include <hip/hip_cooperative_groups.h>

namespace cg = cooperative_groups;

#define DECAY_F 0.99f
#define OMD_F   0.01f
#define EPS_F   1e-5f

typedef __attribute__((ext_vector_type(8)))  __bf16 bf16x8;
typedef __attribute__((ext_vector_type(16))) float  f32x16;

// ---------------- ws layout (byte offsets) ----------------
#define WSB_CNTI     0          // 1024 i32 (4096)
#define WSB_LOSS     4096       // 256 f32 (1024)
#define WSB_DWACC    8192       // 262144 f32 (1 MB)
#define WSB_CSUM     1056768    // 1 f32
#define WSB_ENORM    1056832    // 1024 f32
#define WSB_IDX      1060928    // 32768 i32
#define WSB_EHI      1192000    // 262144 ushort
#define WSB_ELO      1716288    // 262144 ushort
#define WSB_SORT     2240576    // 32768 i32
#define WSB_CURS     2371648    // 1024 i32
#define WSB_BESTD    2375744    // 4*32768 f32
#define WSB_BESTI    2900032    // 4*32768 i32 (end 3424320)

// ---------------- out layout (float offsets) ----------------
#define OUT_ZQ    0
#define OUT_LOSS  8388608
#define OUT_IDX   8388609
#define OUT_EMB   8421377
#define OUT_CS    8683521
#define OUT_EMAW  8684545

// ---------- bf16 split helpers (RNE, no NaN inputs) ----------
__device__ __forceinline__ unsigned short f2bf(float x) {
    unsigned u = __builtin_bit_cast(unsigned, x);
    u += 0x7fffu + ((u >> 16) & 1u);
    return (unsigned short)(u >> 16);
}
__device__ __forceinline__ float bf2f(unsigned short h) {
    return __builtin_bit_cast(float, (unsigned)h << 16);
}
__device__ __forceinline__ void split8(const float4 a, const float4 b,
                                       uint4& hi, uint4& lo) {
    float f[8] = {a.x, a.y, a.z, a.w, b.x, b.y, b.z, b.w};
    unsigned short h[8], l[8];
    #pragma unroll
    for (int i = 0; i < 8; ++i) {
        h[i] = f2bf(f[i]);
        l[i] = f2bf(f[i] - bf2f(h[i]));
    }
    hi.x = (unsigned)h[0] | ((unsigned)h[1] << 16);
    hi.y = (unsigned)h[2] | ((unsigned)h[3] << 16);
    hi.z = (unsigned)h[4] | ((unsigned)h[5] << 16);
    hi.w = (unsigned)h[6] | ((unsigned)h[7] << 16);
    lo.x = (unsigned)l[0] | ((unsigned)l[1] << 16);
    lo.y = (unsigned)l[2] | ((unsigned)l[3] << 16);
    lo.z = (unsigned)l[4] | ((unsigned)l[5] << 16);
    lo.w = (unsigned)l[6] | ((unsigned)l[7] << 16);
}

// ---------- global -> LDS direct 16B copy ----------
__device__ __forceinline__ void load_lds16(const void* g, void* l) {
    __builtin_amdgcn_global_load_lds(
        (const __attribute__((address_space(1))) unsigned int*)g,
        (__attribute__((address_space(3))) unsigned int*)l, 16, 0, 0);
}

// ============ kernel 0: split embedding to bf16 hi/lo + ||e||^2 ============
__global__ __launch_bounds__(256)
void esplit_enorm_kernel(const float* __restrict__ emb,
                         unsigned short* __restrict__ e_hi,
                         unsigned short* __restrict__ e_lo,
                         float* __restrict__ enorm) {
    const int tid = threadIdx.x, lane = tid & 63, wv = tid >> 6;
    const int k = blockIdx.x * 4 + wv;
    const float4 v = *(const float4*)(emb + (size_t)k * 256 + lane * 4);
    float f[4] = {v.x, v.y, v.z, v.w};
    unsigned short h[4], l[4];
    #pragma unroll
    for (int i = 0; i < 4; ++i) { h[i] = f2bf(f[i]); l[i] = f2bf(f[i] - bf2f(h[i])); }
    uint2 hi, lo;
    hi.x = (unsigned)h[0] | ((unsigned)h[1] << 16);
    hi.y = (unsigned)h[2] | ((unsigned)h[3] << 16);
    lo.x = (unsigned)l[0] | ((unsigned)l[1] << 16);
    lo.y = (unsigned)l[2] | ((unsigned)l[3] << 16);
    *(uint2*)(e_hi + (size_t)k * 256 + lane * 4) = hi;
    *(uint2*)(e_lo + (size_t)k * 256 + lane * 4) = lo;
    float s = v.x * v.x + v.y * v.y + v.z * v.z + v.w * v.w;
    #pragma unroll
    for (int off = 32; off > 0; off >>= 1) s += __shfl_down(s, off);
    if (lane == 0) enorm[k] = s;
}

// ============ kernel 1: MFMA argmin (32x32x16, code-split blocks) ============
// Round-0 proven version (95.4 us). Grid 1024 = 256 row-groups x 4 code-splits.
// Block 128 rows x 256 codes, 4 waves (2x2), wave tile 64x128, BK=32.
// 3-combo bf16 hi/lo split. Granule swizzle g_phys = g ^ ((row>>1)&3).
// B staged via global_load_lds (lane-linear LDS; swizzle folded into the
// GLOBAL granule address).
__global__ __launch_bounds__(256, 2)
void argmin_kernel(const float* __restrict__ z,
                   const unsigned short* __restrict__ e_hi,
                   const unsigned short* __restrict__ e_lo,
                   const float* __restrict__ enorm,
                   float* __restrict__ best_d, int* __restrict__ best_i) {
    __shared__ unsigned short Ah[128 * 32], Al[128 * 32];   // 8 KB each
    __shared__ unsigned short Bh[256 * 32], Bl[256 * 32];   // 16 KB each

    const int tid  = threadIdx.x;
    const int lane = tid & 63;
    const int wv   = tid >> 6;
    const int wy   = wv >> 1, wx = wv & 1;
    const int l31  = lane & 31, lh = lane >> 5;
    const int rowg = blockIdx.x & 255;
    const int csp  = blockIdx.x >> 8;
    const int row0 = rowg * 128;
    const int col0 = csp * 256;

    // ---- A staging map (2 granules of 8 floats per thread) ----
    const int rA0 = tid >> 2,  gA = tid & 3;
    const int rA1 = rA0 + 64;
    const float* zA0 = z + (size_t)(row0 + rA0) * 256 + gA * 8;
    const float* zA1 = z + (size_t)(row0 + rA1) * 256 + gA * 8;
    const int offA0 = rA0 * 32 + ((gA ^ ((rA0 >> 1) & 3)) << 3);
    const int offA1 = rA1 * 32 + ((gA ^ ((rA1 >> 1) & 3)) << 3);

    // ---- B staging: 4 lds-direct instrs per array; lane-linear LDS ----
    size_t gBoff[4];
    int    lBoff[4];
    #pragma unroll
    for (int i = 0; i < 4; ++i) {
        const int s = i * 256 + wv * 64 + lane;
        const int c = s >> 2, gp = s & 3;
        const int gl = gp ^ ((c >> 1) & 3);
        gBoff[i] = (size_t)(col0 + c) * 256 + gl * 8;
        lBoff[i] = (i * 256 + wv * 64) * 8;
    }

    // ---- frag read offsets (halfs, swizzled): g_log = kk*2 + lh ----
    int offAf[2][2], offBf[4][2];
    #pragma unroll
    for (int i = 0; i < 2; ++i) {
        const int rt = wy * 64 + i * 32 + l31;
        #pragma unroll
        for (int kk = 0; kk < 2; ++kk)
            offAf[i][kk] = rt * 32 + (((kk * 2 + lh) ^ ((rt >> 1) & 3)) << 3);
    }
    #pragma unroll
    for (int j = 0; j < 4; ++j) {
        const int cb = wx * 128 + j * 32 + l31;
        #pragma unroll
        for (int kk = 0; kk < 2; ++kk)
            offBf[j][kk] = cb * 32 + (((kk * 2 + lh) ^ ((cb >> 1) & 3)) << 3);
    }

    f32x16 acc[2][4];
    #pragma unroll
    for (int i = 0; i < 2; ++i)
        #pragma unroll
        for (int j = 0; j < 4; ++j) acc[i][j] = (f32x16)0.0f;

    float4 pA[4];
    auto prefA = [&](int kc_) {
        const int o = kc_ * 32;
        pA[0] = *(const float4*)(zA0 + o);
        pA[1] = *(const float4*)(zA0 + o + 4);
        pA[2] = *(const float4*)(zA1 + o);
        pA[3] = *(const float4*)(zA1 + o + 4);
    };
    prefA(0);

    for (int kc = 0; kc < 8; ++kc) {
        __syncthreads();
        {   // A: split in regs -> LDS writes
            uint4 h0, l0, h1, l1;
            split8(pA[0], pA[1], h0, l0);
            split8(pA[2], pA[3], h1, l1);
            *(uint4*)(Ah + offA0) = h0; *(uint4*)(Al + offA0) = l0;
            *(uint4*)(Ah + offA1) = h1; *(uint4*)(Al + offA1) = l1;
        }
        // B: global -> LDS direct (drained by the next __syncthreads)
        #pragma unroll
        for (int i = 0; i < 4; ++i) {
            load_lds16(e_hi + gBoff[i] + kc * 32, Bh + lBoff[i]);
            load_lds16(e_lo + gBoff[i] + kc * 32, Bl + lBoff[i]);
        }
        __syncthreads();
        if (kc < 7) prefA(kc + 1);

        #pragma unroll
        for (int kk = 0; kk < 2; ++kk) {
            bf16x8 ah[2], al[2], bh[4], bl[4];
            #pragma unroll
            for (int i = 0; i < 2; ++i) {
                ah[i] = __builtin_bit_cast(bf16x8, *(const uint4*)(Ah + offAf[i][kk]));
                al[i] = __builtin_bit_cast(bf16x8, *(const uint4*)(Al + offAf[i][kk]));
            }
            #pragma unroll
            for (int j = 0; j < 4; ++j) {
                bh[j] = __builtin_bit_cast(bf16x8, *(const uint4*)(Bh + offBf[j][kk]));
                bl[j] = __builtin_bit_cast(bf16x8, *(const uint4*)(Bl + offBf[j][kk]));
            }
            #pragma unroll
            for (int j = 0; j < 4; ++j)
                #pragma unroll
                for (int i = 0; i < 2; ++i)
                    acc[i][j] = __builtin_amdgcn_mfma_f32_32x32x16_bf16(ah[i], bh[j], acc[i][j], 0, 0, 0);
            #pragma unroll
            for (int j = 0; j < 4; ++j)
                #pragma unroll
                for (int i = 0; i < 2; ++i)
                    acc[i][j] = __builtin_amdgcn_mfma_f32_32x32x16_bf16(al[i], bh[j], acc[i][j], 0, 0, 0);
            #pragma unroll
            for (int j = 0; j < 4; ++j)
                #pragma unroll
                for (int i = 0; i < 2; ++i)
                    acc[i][j] = __builtin_amdgcn_mfma_f32_32x32x16_bf16(ah[i], bl[j], acc[i][j], 0, 0, 0);
        }
    }

    // ---- distances + running argmin over j-tiles (codes ascending) ----
    // C layout: col = lane&31, row = (reg&3) + 8*(reg>>2) + 4*(lane>>5)
    float bestd[2][16];
    int   besti[2][16];
    #pragma unroll
    for (int i = 0; i < 2; ++i)
        #pragma unroll
        for (int r = 0; r < 16; ++r) { bestd[i][r] = 3.4e38f; besti[i][r] = 0; }
    #pragma unroll
    for (int j = 0; j < 4; ++j) {
        const int col = col0 + wx * 128 + j * 32 + l31;
        const float en = enorm[col];
        #pragma unroll
        for (int i = 0; i < 2; ++i)
            #pragma unroll
            for (int r = 0; r < 16; ++r) {
                const float d = fmaf(-2.0f, acc[i][j][r], en);
                if (d < bestd[i][r] || (d == bestd[i][r] && col < besti[i][r])) {
                    bestd[i][r] = d; besti[i][r] = col;
                }
            }
    }

    // ---- butterfly over the 32 col lanes (keeps lane>>5 fixed) ----
    #pragma unroll
    for (int m = 1; m < 32; m <<= 1) {
        #pragma unroll
        for (int i = 0; i < 2; ++i)
            #pragma unroll
            for (int r = 0; r < 16; ++r) {
                const float od = __shfl_xor(bestd[i][r], m);
                const int   oi = __shfl_xor(besti[i][r], m);
                if (od < bestd[i][r] || (od == bestd[i][r] && oi < besti[i][r])) {
                    bestd[i][r] = od; besti[i][r] = oi;
                }
            }
    }

    // ---- merge wx halves via LDS, write per-split best ----
    __syncthreads();
    float* mg_d = (float*)Ah;                 // [2][128]
    int*   mg_i = (int*)Ah + 256;
    if (l31 == 0) {
        #pragma unroll
        for (int i = 0; i < 2; ++i)
            #pragma unroll
            for (int r = 0; r < 16; ++r) {
                const int rloc = wy * 64 + i * 32 + (r & 3) + 8 * (r >> 2) + 4 * lh;
                mg_d[wx * 128 + rloc] = bestd[i][r];
                mg_i[wx * 128 + rloc] = besti[i][r];
            }
    }
    __syncthreads();
    if (tid < 128) {
        float d0 = mg_d[tid];             int i0 = mg_i[tid];
        const float d1 = mg_d[128 + tid]; const int i1 = mg_i[128 + tid];
        if (d1 < d0 || (d1 == d0 && i1 < i0)) { d0 = d1; i0 = i1; }
        best_d[csp * 32768 + row0 + tid] = d0;
        best_i[csp * 32768 + row0 + tid] = i0;
    }
}

// ============ kernel 2: fused tail (cooperative) ============
// P0 zero ws accumulators -> P1 merge splits + gather z_q + counts ->
// P2 scan (block 0) -> P3 scatter -> P4 dw+loss run-length -> P5 epilogue.
// 1024 blocks x 256 threads (4 blocks/CU co-resident; low VGPR/LDS).
__global__ __launch_bounds__(256)
void tail_kernel(const float* __restrict__ emb,
                 const float* __restrict__ enorm,
                 const float* __restrict__ z,
                 const float* __restrict__ ema_cs,
                 const float* __restrict__ ema_w,
                 const float* __restrict__ best_d,
                 const int*   __restrict__ best_i,
                 int*   __restrict__ idx,
                 float* __restrict__ idxf,
                 float* __restrict__ out_zq,
                 int*   __restrict__ cnt,
                 float* __restrict__ out_cs,
                 float* __restrict__ csum,
                 int*   __restrict__ cursor,
                 int*   __restrict__ sorted,
                 float* __restrict__ dwacc,
                 float* __restrict__ lossbuf,
                 float* __restrict__ out_emb,
                 float* __restrict__ out_emaw,
                 float* __restrict__ out_loss) {
    cg::grid_group grid = cg::this_grid();
    __shared__ float sh_f[256];
    __shared__ int   sh_i[4];

    const int tid = threadIdx.x;
    const int bid = blockIdx.x;
    const int gthread = bid * 256 + tid;        // 0..262143
    const int lane = tid & 63, wv = tid >> 6;
    const int gw = bid * 4 + wv;                // 0..4095

    // ---- P0: zero cnt / lossbuf / dwacc (replaces hipMemsetAsync) ----
    if (gthread < 65536)
        *(float4*)(dwacc + (size_t)gthread * 4) = make_float4(0.f, 0.f, 0.f, 0.f);
    if (gthread < 1024) cnt[gthread] = 0;
    if (gthread < 256)  lossbuf[gthread] = 0.f;
    grid.sync();

    // ---- P1: merge 4 splits + write idx + gather z_q + counts ----
    // 4096 waves x 8 rows each (contiguous rows per wave).
    #pragma unroll 2
    for (int it = 0; it < 8; ++it) {
        const int n = gw * 8 + it;
        float d = best_d[n]; int i0 = best_i[n];
        #pragma unroll
        for (int s = 1; s < 4; ++s) {
            const float ds = best_d[s * 32768 + n];
            const int   ii = best_i[s * 32768 + n];
            if (ds < d) { d = ds; i0 = ii; }   // splits ascend in code: strict <
        }
        if (lane == 0) { idx[n] = i0; idxf[n] = (float)i0; atomicAdd(&cnt[i0], 1); }
        const float4 e4 = *(const float4*)(emb + (size_t)i0 * 256 + lane * 4);
        *(float4*)(out_zq + (size_t)n * 256 + lane * 4) = e4;
    }
    grid.sync();

    // ---- P2: block 0 scan -> out_cs, csum, exclusive cursor ----
    if (bid == 0) {
        int   c[4];
        int   ls = 0; float fsum = 0.f;
        #pragma unroll
        for (int i = 0; i < 4; ++i) {
            c[i] = cnt[tid * 4 + i];
            const float f = DECAY_F * ema_cs[tid * 4 + i] + OMD_F * (float)c[i];
            out_cs[tid * 4 + i] = f;
            ls += c[i]; fsum += f;
        }
        int v = ls;
        #pragma unroll
        for (int o = 1; o < 64; o <<= 1) { const int u = __shfl_up(v, o); if (lane >= o) v += u; }
        float fs = fsum;
        #pragma unroll
        for (int o = 32; o > 0; o >>= 1) fs += __shfl_down(fs, o);
        if (lane == 63) sh_i[wv] = v;
        if (lane == 0)  sh_f[wv] = fs;
        __syncthreads();
        if (tid == 0) csum[0] = sh_f[0] + sh_f[1] + sh_f[2] + sh_f[3];
        int wbase = 0;
        #pragma unroll
        for (int w = 0; w < 4; ++w) if (w < wv) wbase += sh_i[w];
        int base = wbase + v - ls;               // exclusive prefix for this thread
        #pragma unroll
        for (int i = 0; i < 4; ++i) { cursor[tid * 4 + i] = base; base += c[i]; }
    }
    grid.sync();

    // ---- P3: scatter rows into code-sorted order ----
    if (gthread < 32768) {
        const int k = idx[gthread];
        const int p = atomicAdd(&cursor[k], 1);
        sorted[p] = gthread;
    }
    grid.sync();

    // ---- P4: dw + loss, run-length over 8 sorted rows per wave ----
    {
        const int r0 = gw * 8;
        const int srow = sorted[r0 + (lane & 7)];
        const int skey = idx[srow];

        float4 s4 = make_float4(0.f, 0.f, 0.f, 0.f);
        float sumsq = 0.f;
        int cntr = 0;
        int krun = __shfl(skey, 0);

        auto flush = [&](int k) {
            const float4 e = *(const float4*)(emb + (size_t)k * 256 + lane * 4);
            float val = sumsq - 2.0f * (e.x * s4.x + e.y * s4.y + e.z * s4.z + e.w * s4.w);
            #pragma unroll
            for (int off = 32; off > 0; off >>= 1) val += __shfl_down(val, off);
            if (lane == 0) atomicAdd(&lossbuf[k & 255], val + (float)cntr * enorm[k]);
            float* p = dwacc + (size_t)k * 256 + lane * 4;
            atomicAdd(p + 0, s4.x); atomicAdd(p + 1, s4.y);
            atomicAdd(p + 2, s4.z); atomicAdd(p + 3, s4.w);
        };

        #pragma unroll
        for (int j = 0; j < 8; ++j) {
            const int row = __shfl(srow, j);
            const int k   = __shfl(skey, j);
            if (k != krun) {
                flush(krun);
                s4 = make_float4(0.f, 0.f, 0.f, 0.f);
                sumsq = 0.f; cntr = 0; krun = k;
            }
            const float4 v = *(const float4*)(z + (size_t)row * 256 + lane * 4);
            s4.x += v.x; s4.y += v.y; s4.z += v.z; s4.w += v.w;
            sumsq += v.x * v.x + v.y * v.y + v.z * v.z + v.w * v.w;
            ++cntr;
        }
        flush(krun);
    }
    grid.sync();

    // ---- P5: EMA-w / embedding epilogue + loss finalize ----
    if (bid == 0) {
        sh_f[tid] = lossbuf[tid]; __syncthreads();
        #pragma unroll
        for (int off = 128; off > 0; off >>= 1) {
            if (tid < off) sh_f[tid] += sh_f[tid + off];
            __syncthreads();
        }
        if (tid == 0) out_loss[0] = 1.25f * sh_f[0] / 8388608.0f;
    }
    if (gthread < 65536) {
        const int g = gthread;                   // float4 slot, 0..65535
        const int k = g >> 6;
        const float n_total = csum[0];
        const float cs = (out_cs[k] + EPS_F) / (n_total + 1024.0f * EPS_F) * n_total;

        const float4 w4 = *(const float4*)(ema_w + (size_t)g * 4);
        const float4 d4 = *(const float4*)(dwacc + (size_t)g * 4);
        float4 nw, ne;
        nw.x = DECAY_F * w4.x + OMD_F * d4.x;
        nw.y = DECAY_F * w4.y + OMD_F * d4.y;
        nw.z = DECAY_F * w4.z + OMD_F * d4.z;
        nw.w = DECAY_F * w4.w + OMD_F * d4.w;
        ne.x = nw.x / cs; ne.y = nw.y / cs; ne.z = nw.z / cs; ne.w = nw.w / cs;
        *(float4*)(out_emaw + (size_t)g * 4) = nw;
        *(float4*)(out_emb  + (size_t)g * 4) = ne;
    }
}

// ======================= launcher =======================
extern "C" void kernel_launch(void* const* d_in, const int* in_sizes, int n_in,
                              void* d_out, int out_size, void* d_ws, size_t ws_size,
                              hipStream_t stream) {
    const float* z      = (const float*)d_in[0];
    const float* emb    = (const float*)d_in[1];
    const float* ema_cs = (const float*)d_in[2];
    const float* ema_w  = (const float*)d_in[3];

    float* out = (float*)d_out;
    char*  wsb = (char*)d_ws;

    int*            cnt     = (int*)(wsb + WSB_CNTI);
    float*          lossbuf = (float*)(wsb + WSB_LOSS);
    float*          dwacc   = (float*)(wsb + WSB_DWACC);
    float*          csum    = (float*)(wsb + WSB_CSUM);
    float*          enorm   = (float*)(wsb + WSB_ENORM);
    int*            idx     = (int*)(wsb + WSB_IDX);
    unsigned short* e_hi    = (unsigned short*)(wsb + WSB_EHI);
    unsigned short* e_lo    = (unsigned short*)(wsb + WSB_ELO);
    int*            sorted  = (int*)(wsb + WSB_SORT);
    int*            cursor  = (int*)(wsb + WSB_CURS);
    float*          best_d  = (float*)(wsb + WSB_BESTD);
    int*            best_i  = (int*)(wsb + WSB_BESTI);

    float* out_zq   = out + OUT_ZQ;
    float* out_loss = out + OUT_LOSS;
    float* out_idxf = out + OUT_IDX;
    float* out_emb  = out + OUT_EMB;
    float* out_cs   = out + OUT_CS;
    float* out_emaw = out + OUT_EMAW;

    esplit_enorm_kernel<<<256, 256, 0, stream>>>(emb, e_hi, e_lo, enorm);
    argmin_kernel<<<1024, 256, 0, stream>>>(z, e_hi, e_lo, enorm, best_d, best_i);

    void* args[] = {
        (void*)&emb, (void*)&enorm, (void*)&z, (void*)&ema_cs, (void*)&ema_w,
        (void*)&best_d, (void*)&best_i,
        (void*)&idx, (void*)&out_idxf, (void*)&out_zq, (void*)&cnt,
        (void*)&out_cs, (void*)&csum, (void*)&cursor, (void*)&sorted,
        (void*)&dwacc, (void*)&lossbuf,
        (void*)&out_emb, (void*)&out_emaw, (void*)&out_loss
    };
    hipLaunchCooperativeKernel((const void*)tail_kernel, dim3(1024), dim3(256),
                               args, 0, stream);
}

// Round 4
// 226.656 us; speedup vs baseline: 3.1974x; 3.1974x over previous
//
#include <hip/hip_runtime.h>

#define DECAY_F 0.99f
#define OMD_F   0.01f
#define EPS_F   1e-5f

typedef __attribute__((ext_vector_type(8)))  __bf16 bf16x8;
typedef __attribute__((ext_vector_type(16))) float  f32x16;

// ---------------- ws layout (byte offsets) ----------------
#define WSB_CNTI     0          // 1024 i32 (4096)
#define WSB_LOSS     4096       // 256 f32 (1024)
#define WSB_DWACC    8192       // 262144 f32 (1 MB)
#define WSB_CSUM     1056768    // 1 f32
#define WSB_ENORM    1056832    // 1024 f32
#define WSB_IDX      1060928    // 32768 i32
#define WSB_EHI      1192000    // 262144 ushort
#define WSB_ELO      1716288    // 262144 ushort
#define WSB_SORT     2240576    // 32768 i32
#define WSB_CURS     2371648    // 1024 i32

// ---------------- out layout (float offsets) ----------------
#define OUT_ZQ    0
#define OUT_LOSS  8388608
#define OUT_IDX   8388609
#define OUT_EMB   8421377
#define OUT_CS    8683521
#define OUT_EMAW  8684545

// ---------- bf16 split helpers (RNE, no NaN inputs) ----------
__device__ __forceinline__ unsigned short f2bf(float x) {
    unsigned u = __builtin_bit_cast(unsigned, x);
    u += 0x7fffu + ((u >> 16) & 1u);
    return (unsigned short)(u >> 16);
}
__device__ __forceinline__ float bf2f(unsigned short h) {
    return __builtin_bit_cast(float, (unsigned)h << 16);
}
__device__ __forceinline__ void split8(const float4 a, const float4 b,
                                       uint4& hi, uint4& lo) {
    float f[8] = {a.x, a.y, a.z, a.w, b.x, b.y, b.z, b.w};
    unsigned short h[8], l[8];
    #pragma unroll
    for (int i = 0; i < 8; ++i) {
        h[i] = f2bf(f[i]);
        l[i] = f2bf(f[i] - bf2f(h[i]));
    }
    hi.x = (unsigned)h[0] | ((unsigned)h[1] << 16);
    hi.y = (unsigned)h[2] | ((unsigned)h[3] << 16);
    hi.z = (unsigned)h[4] | ((unsigned)h[5] << 16);
    hi.w = (unsigned)h[6] | ((unsigned)h[7] << 16);
    lo.x = (unsigned)l[0] | ((unsigned)l[1] << 16);
    lo.y = (unsigned)l[2] | ((unsigned)l[3] << 16);
    lo.z = (unsigned)l[4] | ((unsigned)l[5] << 16);
    lo.w = (unsigned)l[6] | ((unsigned)l[7] << 16);
}

// ---------- global -> LDS direct 16B copy ----------
__device__ __forceinline__ void load_lds16(const void* g, void* l) {
    __builtin_amdgcn_global_load_lds(
        (const __attribute__((address_space(1))) unsigned int*)g,
        (__attribute__((address_space(3))) unsigned int*)l, 16, 0, 0);
}

// ============ kernel 0: split embedding + ||e||^2 + zero ws accumulators ============
// Also zeros cnt/lossbuf/dwacc (replaces the hipMemsetAsync dispatch):
// 256 blocks x 256 threads = 65536 threads = exactly one float4 each of dwacc.
__global__ __launch_bounds__(256)
void esplit_enorm_kernel(const float* __restrict__ emb,
                         unsigned short* __restrict__ e_hi,
                         unsigned short* __restrict__ e_lo,
                         float* __restrict__ enorm,
                         float* __restrict__ dwacc,
                         int* __restrict__ cnt,
                         float* __restrict__ lossbuf) {
    const int tid = threadIdx.x, lane = tid & 63, wv = tid >> 6;
    const int gthread = blockIdx.x * 256 + tid;
    *(float4*)(dwacc + (size_t)gthread * 4) = make_float4(0.f, 0.f, 0.f, 0.f);
    if (gthread < 1024) cnt[gthread] = 0;
    if (gthread < 256)  lossbuf[gthread] = 0.f;

    const int k = blockIdx.x * 4 + wv;
    const float4 v = *(const float4*)(emb + (size_t)k * 256 + lane * 4);
    float f[4] = {v.x, v.y, v.z, v.w};
    unsigned short h[4], l[4];
    #pragma unroll
    for (int i = 0; i < 4; ++i) { h[i] = f2bf(f[i]); l[i] = f2bf(f[i] - bf2f(h[i])); }
    uint2 hi, lo;
    hi.x = (unsigned)h[0] | ((unsigned)h[1] << 16);
    hi.y = (unsigned)h[2] | ((unsigned)h[3] << 16);
    lo.x = (unsigned)l[0] | ((unsigned)l[1] << 16);
    lo.y = (unsigned)l[2] | ((unsigned)l[3] << 16);
    *(uint2*)(e_hi + (size_t)k * 256 + lane * 4) = hi;
    *(uint2*)(e_lo + (size_t)k * 256 + lane * 4) = lo;
    float s = v.x * v.x + v.y * v.y + v.z * v.z + v.w * v.w;
    #pragma unroll
    for (int off = 32; off > 0; off >>= 1) s += __shfl_down(s, off);
    if (lane == 0) enorm[k] = s;
}

// ============ kernel 1: MFMA mega-argmin (all 1024 codes per block) ============
// Grid 512 blocks, each 64 rows x 1024 codes. csp-loop of 4 x 256-code splits;
// per split: 8 kc steps of BK=32 with 3-combo bf16 hi/lo MFMA, then fold the
// acc distances into running per-lane best (strict-<, ascending cols -> correct
// ties) and reset acc. 4 waves, wave tile 64x64 per split (acc[2][2]=64 regs).
// Epilogue: butterfly + LDS merge of 4 waves -> FINAL argmin per row; writes
// idx/idxf, atomicAdds counts, and gathers z_q rows from emb (eliminates the
// separate mergegather kernel and the best_d/best_i HBM round-trip).
// Granule swizzle g_phys = g ^ ((row>>1)&3): conflict-free b128 LDS; B staged
// via global_load_lds (lane-linear LDS; swizzle folded into global address).
__global__ __launch_bounds__(256, 2)
void argmin_kernel(const float* __restrict__ z,
                   const unsigned short* __restrict__ e_hi,
                   const unsigned short* __restrict__ e_lo,
                   const float* __restrict__ enorm,
                   const float* __restrict__ emb,
                   int* __restrict__ idx, float* __restrict__ idxf,
                   float* __restrict__ out_zq, int* __restrict__ cnt) {
    __shared__ unsigned short Ah[64 * 32], Al[64 * 32];     // 4 KB each
    __shared__ unsigned short Bh[256 * 32], Bl[256 * 32];   // 16 KB each

    const int tid  = threadIdx.x;
    const int lane = tid & 63;
    const int wv   = tid >> 6;
    const int l31  = lane & 31, lh = lane >> 5;
    const int row0 = blockIdx.x * 64;

    // ---- A staging map (1 granule of 8 floats per thread) ----
    const int rA = tid >> 2, gA = tid & 3;
    const float* zA = z + (size_t)(row0 + rA) * 256 + gA * 8;
    const int offA = rA * 32 + ((gA ^ ((rA >> 1) & 3)) << 3);

    // ---- B staging: 4 lds-direct instrs per array; lane-linear LDS ----
    int gBoff[4], lBoff[4];
    #pragma unroll
    for (int i = 0; i < 4; ++i) {
        const int s = i * 256 + wv * 64 + lane;
        const int c = s >> 2, gp = s & 3;
        const int gl = gp ^ ((c >> 1) & 3);
        gBoff[i] = c * 256 + gl * 8;
        lBoff[i] = (i * 256 + wv * 64) * 8;
    }

    // ---- frag read offsets (halfs, swizzled): g_log = kk*2 + lh ----
    int offAf[2][2], offBf[2][2];
    #pragma unroll
    for (int i = 0; i < 2; ++i) {
        const int rt = i * 32 + l31;
        #pragma unroll
        for (int kk = 0; kk < 2; ++kk)
            offAf[i][kk] = rt * 32 + (((kk * 2 + lh) ^ ((rt >> 1) & 3)) << 3);
    }
    #pragma unroll
    for (int j = 0; j < 2; ++j) {
        const int cb = wv * 64 + j * 32 + l31;
        #pragma unroll
        for (int kk = 0; kk < 2; ++kk)
            offBf[j][kk] = cb * 32 + (((kk * 2 + lh) ^ ((cb >> 1) & 3)) << 3);
    }

    f32x16 acc[2][2];
    #pragma unroll
    for (int i = 0; i < 2; ++i)
        #pragma unroll
        for (int j = 0; j < 2; ++j) acc[i][j] = (f32x16)0.0f;

    float bestd[2][16];
    int   besti[2][16];
    #pragma unroll
    for (int i = 0; i < 2; ++i)
        #pragma unroll
        for (int r = 0; r < 16; ++r) { bestd[i][r] = 3.4e38f; besti[i][r] = 0; }

    float4 pA[2];
    auto prefA = [&](int kc_) {
        const int o = kc_ * 32;
        pA[0] = *(const float4*)(zA + o);
        pA[1] = *(const float4*)(zA + o + 4);
    };
    prefA(0);

    for (int csp = 0; csp < 4; ++csp) {
        const int ebase = csp * 65536;          // 256 codes * 256 dims per split

        for (int kc = 0; kc < 8; ++kc) {
            __syncthreads();
            {   // A: split in regs -> LDS writes (same data each csp; L2-hot reload)
                uint4 h0, l0;
                split8(pA[0], pA[1], h0, l0);
                *(uint4*)(Ah + offA) = h0; *(uint4*)(Al + offA) = l0;
            }
            // B: global -> LDS direct (drained by the next __syncthreads)
            #pragma unroll
            for (int i = 0; i < 4; ++i) {
                load_lds16(e_hi + ebase + gBoff[i] + kc * 32, Bh + lBoff[i]);
                load_lds16(e_lo + ebase + gBoff[i] + kc * 32, Bl + lBoff[i]);
            }
            __syncthreads();
            if (kc < 7) prefA(kc + 1);
            else if (csp < 3) prefA(0);

            #pragma unroll
            for (int kk = 0; kk < 2; ++kk) {
                bf16x8 ah[2], al[2], bh[2], bl[2];
                #pragma unroll
                for (int i = 0; i < 2; ++i) {
                    ah[i] = __builtin_bit_cast(bf16x8, *(const uint4*)(Ah + offAf[i][kk]));
                    al[i] = __builtin_bit_cast(bf16x8, *(const uint4*)(Al + offAf[i][kk]));
                }
                #pragma unroll
                for (int j = 0; j < 2; ++j) {
                    bh[j] = __builtin_bit_cast(bf16x8, *(const uint4*)(Bh + offBf[j][kk]));
                    bl[j] = __builtin_bit_cast(bf16x8, *(const uint4*)(Bl + offBf[j][kk]));
                }
                #pragma unroll
                for (int j = 0; j < 2; ++j)
                    #pragma unroll
                    for (int i = 0; i < 2; ++i)
                        acc[i][j] = __builtin_amdgcn_mfma_f32_32x32x16_bf16(ah[i], bh[j], acc[i][j], 0, 0, 0);
                #pragma unroll
                for (int j = 0; j < 2; ++j)
                    #pragma unroll
                    for (int i = 0; i < 2; ++i)
                        acc[i][j] = __builtin_amdgcn_mfma_f32_32x32x16_bf16(al[i], bh[j], acc[i][j], 0, 0, 0);
                #pragma unroll
                for (int j = 0; j < 2; ++j)
                    #pragma unroll
                    for (int i = 0; i < 2; ++i)
                        acc[i][j] = __builtin_amdgcn_mfma_f32_32x32x16_bf16(ah[i], bl[j], acc[i][j], 0, 0, 0);
            }
        }

        // ---- fold this split's distances into running best; reset acc ----
        // C layout: col = lane&31, row = (reg&3) + 8*(reg>>2) + 4*(lane>>5)
        #pragma unroll
        for (int j = 0; j < 2; ++j) {
            const int col = csp * 256 + wv * 64 + j * 32 + l31;
            const float en = enorm[col];
            #pragma unroll
            for (int i = 0; i < 2; ++i)
                #pragma unroll
                for (int r = 0; r < 16; ++r) {
                    const float d = fmaf(-2.0f, acc[i][j][r], en);
                    if (d < bestd[i][r] || (d == bestd[i][r] && col < besti[i][r])) {
                        bestd[i][r] = d; besti[i][r] = col;
                    }
                }
        }
        #pragma unroll
        for (int i = 0; i < 2; ++i)
            #pragma unroll
            for (int j = 0; j < 2; ++j) acc[i][j] = (f32x16)0.0f;
    }

    // ---- butterfly over the 32 col lanes (keeps lane>>5 fixed) ----
    #pragma unroll
    for (int m = 1; m < 32; m <<= 1) {
        #pragma unroll
        for (int i = 0; i < 2; ++i)
            #pragma unroll
            for (int r = 0; r < 16; ++r) {
                const float od = __shfl_xor(bestd[i][r], m);
                const int   oi = __shfl_xor(besti[i][r], m);
                if (od < bestd[i][r] || (od == bestd[i][r] && oi < besti[i][r])) {
                    bestd[i][r] = od; besti[i][r] = oi;
                }
            }
    }

    // ---- merge the 4 waves via LDS -> FINAL argmin; write idx/counts ----
    __syncthreads();
    float* mg_d = (float*)Ah;                 // [4][64] floats
    int*   mg_i = (int*)Ah + 256;             // [4][64] ints
    if (l31 == 0) {
        #pragma unroll
        for (int i = 0; i < 2; ++i)
            #pragma unroll
            for (int r = 0; r < 16; ++r) {
                const int rloc = i * 32 + (r & 3) + 8 * (r >> 2) + 4 * lh;
                mg_d[wv * 64 + rloc] = bestd[i][r];
                mg_i[wv * 64 + rloc] = besti[i][r];
            }
    }
    __syncthreads();
    if (tid < 64) {
        float d0 = mg_d[tid];
        int   i0 = mg_i[tid];
        #pragma unroll
        for (int w = 1; w < 4; ++w) {   // wave col-ranges interleave: full comparator
            const float dw = mg_d[w * 64 + tid];
            const int   iw = mg_i[w * 64 + tid];
            if (dw < d0 || (dw == d0 && iw < i0)) { d0 = dw; i0 = iw; }
        }
        const int n = row0 + tid;
        idx[n] = i0; idxf[n] = (float)i0;
        atomicAdd(&cnt[i0], 1);
        mg_i[tid] = i0;                  // publish final codes for the gather
    }
    __syncthreads();

    // ---- gather z_q: each wave writes 16 rows (emb is L2/L3-resident) ----
    #pragma unroll 4
    for (int r = 0; r < 16; ++r) {
        const int row = wv * 16 + r;
        const int code = mg_i[row];
        const float4 e4 = *(const float4*)(emb + (size_t)code * 256 + lane * 4);
        *(float4*)(out_zq + (size_t)(row0 + row) * 256 + lane * 4) = e4;
    }
}

// ============ kernel 2: scan — out_cs, csum, exclusive cursor ============
__global__ __launch_bounds__(1024)
void scan_kernel(const float* __restrict__ ema_cs, const int* __restrict__ cnt,
                 float* __restrict__ out_cs, float* __restrict__ csum,
                 int* __restrict__ cursor) {
    __shared__ int   wtmp[16];
    __shared__ float wred[16];
    const int t = threadIdx.x, lane = t & 63, wv = t >> 6;
    const int c = cnt[t];
    const float f = DECAY_F * ema_cs[t] + OMD_F * (float)c;
    out_cs[t] = f;
    float fs = f;
    #pragma unroll
    for (int o = 32; o > 0; o >>= 1) fs += __shfl_down(fs, o);
    if (lane == 0) wred[wv] = fs;
    int v = c;
    #pragma unroll
    for (int o = 1; o < 64; o <<= 1) { const int u = __shfl_up(v, o); if (lane >= o) v += u; }
    if (lane == 63) wtmp[wv] = v;
    __syncthreads();
    if (t == 0) { float s2 = 0.f; for (int w = 0; w < 16; ++w) s2 += wred[w]; csum[0] = s2; }
    int wbase = 0;
    #pragma unroll
    for (int w = 0; w < 16; ++w) if (w < wv) wbase += wtmp[w];
    cursor[t] = wbase + v - c;
}

// ============ kernel 3: scatter rows into code-sorted order ============
__global__ __launch_bounds__(256)
void scatter_kernel(const int* __restrict__ idx, int* __restrict__ cursor,
                    int* __restrict__ sorted) {
    const int n = blockIdx.x * 256 + threadIdx.x;
    const int k = idx[n];
    const int p = atomicAdd(&cursor[k], 1);
    sorted[p] = n;
}

// ============ kernel 4: dw + loss — wave per 16 sorted rows, run-length ============
// loss per run computed algebraically: sum||z-e||^2 = sum(z^2) - 2 e.S + cnt*||e||^2
__global__ __launch_bounds__(256)
void dw_kernel(const float* __restrict__ z, const float* __restrict__ emb,
               const float* __restrict__ enorm,
               const int* __restrict__ sorted, const int* __restrict__ idx,
               float* __restrict__ dwacc, float* __restrict__ lossbuf) {
    const int lane = threadIdx.x & 63;
    const int w    = blockIdx.x * 4 + (threadIdx.x >> 6);
    const int r0   = w * 16;
    const int srow = sorted[r0 + (lane & 15)];
    const int skey = idx[srow];

    float4 s = make_float4(0.f, 0.f, 0.f, 0.f);
    float sumsq = 0.f;
    int cntr = 0;
    int krun = __shfl(skey, 0);

    auto flush = [&](int k) {
        const float4 e = *(const float4*)(emb + (size_t)k * 256 + lane * 4);
        float val = sumsq - 2.0f * (e.x * s.x + e.y * s.y + e.z * s.z + e.w * s.w);
        #pragma unroll
        for (int off = 32; off > 0; off >>= 1) val += __shfl_down(val, off);
        if (lane == 0) atomicAdd(&lossbuf[k & 255], val + (float)cntr * enorm[k]);
        float* p = dwacc + (size_t)k * 256 + lane * 4;
        atomicAdd(p + 0, s.x); atomicAdd(p + 1, s.y);
        atomicAdd(p + 2, s.z); atomicAdd(p + 3, s.w);
    };

    #pragma unroll 8
    for (int j = 0; j < 16; ++j) {
        const int row = __shfl(srow, j);
        const int k   = __shfl(skey, j);
        if (k != krun) {
            flush(krun);
            s = make_float4(0.f, 0.f, 0.f, 0.f);
            sumsq = 0.f; cntr = 0; krun = k;
        }
        const float4 v = *(const float4*)(z + (size_t)row * 256 + lane * 4);
        s.x += v.x; s.y += v.y; s.z += v.z; s.w += v.w;
        sumsq += v.x * v.x + v.y * v.y + v.z * v.z + v.w * v.w;
        ++cntr;
    }
    flush(krun);
}

// ============ kernel 5: EMA-w / embedding epilogue + loss finalize ============
__global__ __launch_bounds__(256)
void update_w_kernel(const float* __restrict__ ema_w, const float* __restrict__ dwacc,
                     const float* __restrict__ out_cs, const float* __restrict__ csum,
                     const float* __restrict__ lossbuf,
                     float* __restrict__ out_emb, float* __restrict__ out_emaw,
                     float* __restrict__ out_loss) {
    __shared__ float red[256];
    const int t = threadIdx.x;
    if (blockIdx.x == 0) {
        red[t] = lossbuf[t]; __syncthreads();
        #pragma unroll
        for (int off = 128; off > 0; off >>= 1) {
            if (t < off) red[t] += red[t + off];
            __syncthreads();
        }
        if (t == 0) out_loss[0] = 1.25f * red[0] / 8388608.0f;
    }

    const int g = blockIdx.x * 256 + t;          // float4 slot, 0..65535
    const int k = g >> 6;
    const float n_total = csum[0];
    const float cs = (out_cs[k] + EPS_F) / (n_total + 1024.0f * EPS_F) * n_total;

    const float4 w4 = *(const float4*)(ema_w + (size_t)g * 4);
    const float4 d4 = *(const float4*)(dwacc + (size_t)g * 4);
    float4 nw, ne;
    nw.x = DECAY_F * w4.x + OMD_F * d4.x;
    nw.y = DECAY_F * w4.y + OMD_F * d4.y;
    nw.z = DECAY_F * w4.z + OMD_F * d4.z;
    nw.w = DECAY_F * w4.w + OMD_F * d4.w;
    ne.x = nw.x / cs; ne.y = nw.y / cs; ne.z = nw.z / cs; ne.w = nw.w / cs;
    *(float4*)(out_emaw + (size_t)g * 4) = nw;
    *(float4*)(out_emb  + (size_t)g * 4) = ne;
}

// ======================= launcher =======================
extern "C" void kernel_launch(void* const* d_in, const int* in_sizes, int n_in,
                              void* d_out, int out_size, void* d_ws, size_t ws_size,
                              hipStream_t stream) {
    const float* z      = (const float*)d_in[0];
    const float* emb    = (const float*)d_in[1];
    const float* ema_cs = (const float*)d_in[2];
    const float* ema_w  = (const float*)d_in[3];

    float* out = (float*)d_out;
    char*  wsb = (char*)d_ws;

    int*            cnt     = (int*)(wsb + WSB_CNTI);
    float*          lossbuf = (float*)(wsb + WSB_LOSS);
    float*          dwacc   = (float*)(wsb + WSB_DWACC);
    float*          csum    = (float*)(wsb + WSB_CSUM);
    float*          enorm   = (float*)(wsb + WSB_ENORM);
    int*            idx     = (int*)(wsb + WSB_IDX);
    unsigned short* e_hi    = (unsigned short*)(wsb + WSB_EHI);
    unsigned short* e_lo    = (unsigned short*)(wsb + WSB_ELO);
    int*            sorted  = (int*)(wsb + WSB_SORT);
    int*            cursor  = (int*)(wsb + WSB_CURS);

    float* out_zq   = out + OUT_ZQ;
    float* out_loss = out + OUT_LOSS;
    float* out_idxf = out + OUT_IDX;
    float* out_emb  = out + OUT_EMB;
    float* out_cs   = out + OUT_CS;
    float* out_emaw = out + OUT_EMAW;

    esplit_enorm_kernel<<<256, 256, 0, stream>>>(emb, e_hi, e_lo, enorm,
                                                 dwacc, cnt, lossbuf);
    argmin_kernel<<<512, 256, 0, stream>>>(z, e_hi, e_lo, enorm, emb,
                                           idx, out_idxf, out_zq, cnt);
    scan_kernel<<<1, 1024, 0, stream>>>(ema_cs, cnt, out_cs, csum, cursor);
    scatter_kernel<<<128, 256, 0, stream>>>(idx, cursor, sorted);
    dw_kernel<<<512, 256, 0, stream>>>(z, emb, enorm, sorted, idx, dwacc, lossbuf);
    update_w_kernel<<<256, 256, 0, stream>>>(ema_w, dwacc, out_cs, csum, lossbuf,
                                             out_emb, out_emaw, out_loss);
}

// Round 5
// 206.882 us; speedup vs baseline: 3.5030x; 1.0956x over previous
//
#include <hip/hip_runtime.h>

#define DECAY_F 0.99f
#define OMD_F   0.01f
#define EPS_F   1e-5f

typedef __attribute__((ext_vector_type(8)))  __bf16 bf16x8;
typedef __attribute__((ext_vector_type(16))) float  f32x16;

// ---------------- ws layout (byte offsets) ----------------
#define WSB_CNTI     0          // 1024 i32 (4096)
#define WSB_LOSS     4096       // 256 f32 (1024)
#define WSB_DWACC    8192       // 262144 f32 (1 MB)
#define WSB_CSUM     1056768    // 1 f32
#define WSB_ENORM    1056832    // 1024 f32
#define WSB_IDX      1060928    // 32768 i32
#define WSB_EHI      1192000    // 262144 ushort (FRAG layout)
#define WSB_ELO      1716288    // 262144 ushort (FRAG layout)
#define WSB_SORT     2240576    // 32768 i32
#define WSB_CURS     2371648    // 1024 i32

// ---------------- out layout (float offsets) ----------------
#define OUT_ZQ    0
#define OUT_LOSS  8388608
#define OUT_IDX   8388609
#define OUT_EMB   8421377
#define OUT_CS    8683521
#define OUT_EMAW  8684545

// ---------- bf16 split helpers (RNE, no NaN inputs) ----------
__device__ __forceinline__ unsigned short f2bf(float x) {
    unsigned u = __builtin_bit_cast(unsigned, x);
    u += 0x7fffu + ((u >> 16) & 1u);
    return (unsigned short)(u >> 16);
}
__device__ __forceinline__ float bf2f(unsigned short h) {
    return __builtin_bit_cast(float, (unsigned)h << 16);
}
__device__ __forceinline__ void split8(const float4 a, const float4 b,
                                       uint4& hi, uint4& lo) {
    float f[8] = {a.x, a.y, a.z, a.w, b.x, b.y, b.z, b.w};
    unsigned short h[8], l[8];
    #pragma unroll
    for (int i = 0; i < 8; ++i) {
        h[i] = f2bf(f[i]);
        l[i] = f2bf(f[i] - bf2f(h[i]));
    }
    hi.x = (unsigned)h[0] | ((unsigned)h[1] << 16);
    hi.y = (unsigned)h[2] | ((unsigned)h[3] << 16);
    hi.z = (unsigned)h[4] | ((unsigned)h[5] << 16);
    hi.w = (unsigned)h[6] | ((unsigned)h[7] << 16);
    lo.x = (unsigned)l[0] | ((unsigned)l[1] << 16);
    lo.y = (unsigned)l[2] | ((unsigned)l[3] << 16);
    lo.z = (unsigned)l[4] | ((unsigned)l[5] << 16);
    lo.w = (unsigned)l[6] | ((unsigned)l[7] << 16);
}

// ============ kernel 0: esplit (FRAG layout) + ||e||^2 + zero ws ============
// B' fragment layout: chunk = (g*8 + kc)*2 + kk (g = code>>5, kc = K-step,
// kk = K-half); within a chunk, lane (lh*32+l31) holds code g*32+l31, dims
// kc*32 + (kk*2+lh)*8 .. +8 as 8 bf16 = 16 B. One chunk = 1 KB, so an
// argmin wave's B-fragment load is ONE fully-coalesced 1 KB global load.
__global__ __launch_bounds__(256)
void esplit_enorm_kernel(const float* __restrict__ emb,
                         unsigned short* __restrict__ e_hi,
                         unsigned short* __restrict__ e_lo,
                         float* __restrict__ enorm,
                         float* __restrict__ dwacc,
                         int* __restrict__ cnt,
                         float* __restrict__ lossbuf) {
    const int tid = threadIdx.x, lane = tid & 63, wv = tid >> 6;
    const int gthread = blockIdx.x * 256 + tid;

    // zero accumulators (replaces hipMemsetAsync)
    *(float4*)(dwacc + (size_t)gthread * 4) = make_float4(0.f, 0.f, 0.f, 0.f);
    if (gthread < 1024) cnt[gthread] = 0;
    if (gthread < 256)  lossbuf[gthread] = 0.f;

    // frag-layout split: threads 0..32767, one 8-dim granule each
    if (gthread < 32768) {
        const int F     = gthread;
        const int chunk = F >> 6;            // (g*8+kc)*2+kk
        const int lh6   = (F >> 5) & 1;
        const int l31f  = F & 31;
        const int g     = chunk >> 4;
        const int kc    = (chunk >> 1) & 7;
        const int kk    = chunk & 1;
        const int k     = g * 32 + l31f;
        const int d0    = kc * 32 + (kk * 2 + lh6) * 8;
        const float4 v0 = *(const float4*)(emb + (size_t)k * 256 + d0);
        const float4 v1 = *(const float4*)(emb + (size_t)k * 256 + d0 + 4);
        uint4 h, l;
        split8(v0, v1, h, l);
        *(uint4*)((char*)e_hi + (size_t)F * 16) = h;
        *(uint4*)((char*)e_lo + (size_t)F * 16) = l;
    }

    // ||e||^2: wave per code (4 codes per block), coalesced row read
    const int k = blockIdx.x * 4 + wv;
    const float4 v = *(const float4*)(emb + (size_t)k * 256 + lane * 4);
    float s = v.x * v.x + v.y * v.y + v.z * v.z + v.w * v.w;
    #pragma unroll
    for (int off = 32; off > 0; off >>= 1) s += __shfl_down(s, off);
    if (lane == 0) enorm[k] = s;
}

// ============ kernel 1: barrier-free MFMA mega-argmin ============
// Grid 512 blocks (= exactly 2 resident/CU), 64 rows x 1024 codes per block.
// A (z rows) split hi/lo ONCE into full-K=256 LDS fragment layout (32 KB x2,
// chunk C = (i*8+kc)*2+kk, lane-linear 16 B -> conflict-free ds_read_b128).
// B fragments loaded straight from the esplit frag layout: 1 KB coalesced
// global loads into REGISTERS (L2-resident, no LDS, no barrier). Steady-state
// loop s=0..31 (csp = s>>3, kc = s&7) has NO __syncthreads: 8 ds_reads +
// 8 global loads (prefetched 1 step ahead, ping-pong regs) + 24 MFMA.
// Per-CU budget: MFMA 1536 cyc vs LDS ~770 vs L2 ~500 -> MFMA-bound.
// Epilogue (round-4): butterfly + LDS merge -> final argmin; writes idx/idxf,
// counts, gathers z_q.
__global__ __launch_bounds__(256, 2)
void argmin_kernel(const float* __restrict__ z,
                   const unsigned short* __restrict__ e_hi,
                   const unsigned short* __restrict__ e_lo,
                   const float* __restrict__ enorm,
                   const float* __restrict__ emb,
                   int* __restrict__ idx, float* __restrict__ idxf,
                   float* __restrict__ out_zq, int* __restrict__ cnt) {
    __shared__ unsigned short Ah[32 * 512], Al[32 * 512];   // 32 KB each

    const int tid  = threadIdx.x;
    const int lane = tid & 63;
    const int wv   = tid >> 6;
    const int l31  = lane & 31, lh = lane >> 5;
    const int row0 = blockIdx.x * 64;

    // ---- A init: split 64 rows x 256 dims into frag-layout LDS, once ----
    #pragma unroll
    for (int c8 = 0; c8 < 8; ++c8) {
        const int C  = wv * 8 + c8;
        const int i  = C >> 4, kc = (C >> 1) & 7, kk = C & 1;
        const int row = row0 + i * 32 + l31;
        const int d0  = kc * 32 + (kk * 2 + lh) * 8;
        const float4 v0 = *(const float4*)(z + (size_t)row * 256 + d0);
        const float4 v1 = *(const float4*)(z + (size_t)row * 256 + d0 + 4);
        uint4 h, l;
        split8(v0, v1, h, l);
        *(uint4*)((char*)Ah + (size_t)C * 1024 + lane * 16) = h;
        *(uint4*)((char*)Al + (size_t)C * 1024 + lane * 16) = l;
    }
    __syncthreads();     // the ONLY barrier before the epilogue

    f32x16 acc[2][2];
    #pragma unroll
    for (int i = 0; i < 2; ++i)
        #pragma unroll
        for (int j = 0; j < 2; ++j) acc[i][j] = (f32x16)0.0f;

    float bestd[2][16];
    int   besti[2][16];
    #pragma unroll
    for (int i = 0; i < 2; ++i)
        #pragma unroll
        for (int r = 0; r < 16; ++r) { bestd[i][r] = 3.4e38f; besti[i][r] = 0; }

    // B fragment loads: chunk = g*16 + kc*2 + kk, g = csp*8 + wv*2 + j
    uint4 b0h[4], b0l[4], b1h[4], b1l[4];
    auto loadB = [&](int s, uint4* bh, uint4* bl) {
        const int csp = s >> 3, kc = s & 7;
        #pragma unroll
        for (int j = 0; j < 2; ++j)
            #pragma unroll
            for (int kk = 0; kk < 2; ++kk) {
                const int chunk = (csp * 8 + wv * 2 + j) * 16 + kc * 2 + kk;
                bh[j * 2 + kk] = *(const uint4*)((const char*)e_hi + (size_t)chunk * 1024 + lane * 16);
                bl[j * 2 + kk] = *(const uint4*)((const char*)e_lo + (size_t)chunk * 1024 + lane * 16);
            }
    };
    auto compute = [&](int s, const uint4* bh4, const uint4* bl4) {
        const int kc = s & 7;
        #pragma unroll
        for (int kk = 0; kk < 2; ++kk) {
            bf16x8 bh[2], bl[2];
            #pragma unroll
            for (int j = 0; j < 2; ++j) {
                bh[j] = __builtin_bit_cast(bf16x8, bh4[j * 2 + kk]);
                bl[j] = __builtin_bit_cast(bf16x8, bl4[j * 2 + kk]);
            }
            #pragma unroll
            for (int i = 0; i < 2; ++i) {
                const int C = i * 16 + kc * 2 + kk;
                const bf16x8 ah = __builtin_bit_cast(bf16x8,
                    *(const uint4*)((const char*)Ah + (size_t)C * 1024 + lane * 16));
                const bf16x8 al = __builtin_bit_cast(bf16x8,
                    *(const uint4*)((const char*)Al + (size_t)C * 1024 + lane * 16));
                #pragma unroll
                for (int j = 0; j < 2; ++j) {
                    acc[i][j] = __builtin_amdgcn_mfma_f32_32x32x16_bf16(ah, bh[j], acc[i][j], 0, 0, 0);
                    acc[i][j] = __builtin_amdgcn_mfma_f32_32x32x16_bf16(al, bh[j], acc[i][j], 0, 0, 0);
                    acc[i][j] = __builtin_amdgcn_mfma_f32_32x32x16_bf16(ah, bl[j], acc[i][j], 0, 0, 0);
                }
            }
        }
        if ((s & 7) == 7) {   // end of this 256-code split: fold distances
            const int csp = s >> 3;
            #pragma unroll
            for (int j = 0; j < 2; ++j) {
                const int col = csp * 256 + wv * 64 + j * 32 + l31;
                const float en = enorm[col];
                #pragma unroll
                for (int i = 0; i < 2; ++i)
                    #pragma unroll
                    for (int r = 0; r < 16; ++r) {
                        const float d = fmaf(-2.0f, acc[i][j][r], en);
                        if (d < bestd[i][r] || (d == bestd[i][r] && col < besti[i][r])) {
                            bestd[i][r] = d; besti[i][r] = col;
                        }
                    }
            }
            #pragma unroll
            for (int i = 0; i < 2; ++i)
                #pragma unroll
                for (int j = 0; j < 2; ++j) acc[i][j] = (f32x16)0.0f;
        }
    };

    loadB(0, b0h, b0l);
    for (int s = 0; s < 32; s += 2) {
        loadB(s + 1, b1h, b1l);
        compute(s, b0h, b0l);
        if (s + 2 < 32) loadB(s + 2, b0h, b0l);
        compute(s + 1, b1h, b1l);
    }

    // ---- butterfly over the 32 col lanes (keeps lane>>5 fixed) ----
    #pragma unroll
    for (int m = 1; m < 32; m <<= 1) {
        #pragma unroll
        for (int i = 0; i < 2; ++i)
            #pragma unroll
            for (int r = 0; r < 16; ++r) {
                const float od = __shfl_xor(bestd[i][r], m);
                const int   oi = __shfl_xor(besti[i][r], m);
                if (od < bestd[i][r] || (od == bestd[i][r] && oi < besti[i][r])) {
                    bestd[i][r] = od; besti[i][r] = oi;
                }
            }
    }

    // ---- merge the 4 waves via LDS -> FINAL argmin; write idx/counts ----
    __syncthreads();
    float* mg_d = (float*)Ah;                 // [4][64] floats
    int*   mg_i = (int*)Ah + 256;             // [4][64] ints
    if (l31 == 0) {
        #pragma unroll
        for (int i = 0; i < 2; ++i)
            #pragma unroll
            for (int r = 0; r < 16; ++r) {
                const int rloc = i * 32 + (r & 3) + 8 * (r >> 2) + 4 * lh;
                mg_d[wv * 64 + rloc] = bestd[i][r];
                mg_i[wv * 64 + rloc] = besti[i][r];
            }
    }
    __syncthreads();
    if (tid < 64) {
        float d0 = mg_d[tid];
        int   i0 = mg_i[tid];
        #pragma unroll
        for (int w = 1; w < 4; ++w) {   // wave col-ranges interleave: full comparator
            const float dw = mg_d[w * 64 + tid];
            const int   iw = mg_i[w * 64 + tid];
            if (dw < d0 || (dw == d0 && iw < i0)) { d0 = dw; i0 = iw; }
        }
        const int n = row0 + tid;
        idx[n] = i0; idxf[n] = (float)i0;
        atomicAdd(&cnt[i0], 1);
        mg_i[tid] = i0;                  // publish final codes for the gather
    }
    __syncthreads();

    // ---- gather z_q: each wave writes 16 rows (emb is L2/L3-resident) ----
    #pragma unroll 4
    for (int r = 0; r < 16; ++r) {
        const int row = wv * 16 + r;
        const int code = mg_i[row];
        const float4 e4 = *(const float4*)(emb + (size_t)code * 256 + lane * 4);
        *(float4*)(out_zq + (size_t)(row0 + row) * 256 + lane * 4) = e4;
    }
}

// ============ kernel 2: scan — out_cs, csum, exclusive cursor ============
__global__ __launch_bounds__(1024)
void scan_kernel(const float* __restrict__ ema_cs, const int* __restrict__ cnt,
                 float* __restrict__ out_cs, float* __restrict__ csum,
                 int* __restrict__ cursor) {
    __shared__ int   wtmp[16];
    __shared__ float wred[16];
    const int t = threadIdx.x, lane = t & 63, wv = t >> 6;
    const int c = cnt[t];
    const float f = DECAY_F * ema_cs[t] + OMD_F * (float)c;
    out_cs[t] = f;
    float fs = f;
    #pragma unroll
    for (int o = 32; o > 0; o >>= 1) fs += __shfl_down(fs, o);
    if (lane == 0) wred[wv] = fs;
    int v = c;
    #pragma unroll
    for (int o = 1; o < 64; o <<= 1) { const int u = __shfl_up(v, o); if (lane >= o) v += u; }
    if (lane == 63) wtmp[wv] = v;
    __syncthreads();
    if (t == 0) { float s2 = 0.f; for (int w = 0; w < 16; ++w) s2 += wred[w]; csum[0] = s2; }
    int wbase = 0;
    #pragma unroll
    for (int w = 0; w < 16; ++w) if (w < wv) wbase += wtmp[w];
    cursor[t] = wbase + v - c;
}

// ============ kernel 3: scatter rows into code-sorted order ============
__global__ __launch_bounds__(256)
void scatter_kernel(const int* __restrict__ idx, int* __restrict__ cursor,
                    int* __restrict__ sorted) {
    const int n = blockIdx.x * 256 + threadIdx.x;
    const int k = idx[n];
    const int p = atomicAdd(&cursor[k], 1);
    sorted[p] = n;
}

// ============ kernel 4: dw + loss — wave per 16 sorted rows, run-length ============
__global__ __launch_bounds__(256)
void dw_kernel(const float* __restrict__ z, const float* __restrict__ emb,
               const float* __restrict__ enorm,
               const int* __restrict__ sorted, const int* __restrict__ idx,
               float* __restrict__ dwacc, float* __restrict__ lossbuf) {
    const int lane = threadIdx.x & 63;
    const int w    = blockIdx.x * 4 + (threadIdx.x >> 6);
    const int r0   = w * 16;
    const int srow = sorted[r0 + (lane & 15)];
    const int skey = idx[srow];

    float4 s = make_float4(0.f, 0.f, 0.f, 0.f);
    float sumsq = 0.f;
    int cntr = 0;
    int krun = __shfl(skey, 0);

    auto flush = [&](int k) {
        const float4 e = *(const float4*)(emb + (size_t)k * 256 + lane * 4);
        float val = sumsq - 2.0f * (e.x * s.x + e.y * s.y + e.z * s.z + e.w * s.w);
        #pragma unroll
        for (int off = 32; off > 0; off >>= 1) val += __shfl_down(val, off);
        if (lane == 0) atomicAdd(&lossbuf[k & 255], val + (float)cntr * enorm[k]);
        float* p = dwacc + (size_t)k * 256 + lane * 4;
        atomicAdd(p + 0, s.x); atomicAdd(p + 1, s.y);
        atomicAdd(p + 2, s.z); atomicAdd(p + 3, s.w);
    };

    #pragma unroll 8
    for (int j = 0; j < 16; ++j) {
        const int row = __shfl(srow, j);
        const int k   = __shfl(skey, j);
        if (k != krun) {
            flush(krun);
            s = make_float4(0.f, 0.f, 0.f, 0.f);
            sumsq = 0.f; cntr = 0; krun = k;
        }
        const float4 v = *(const float4*)(z + (size_t)row * 256 + lane * 4);
        s.x += v.x; s.y += v.y; s.z += v.z; s.w += v.w;
        sumsq += v.x * v.x + v.y * v.y + v.z * v.z + v.w * v.w;
        ++cntr;
    }
    flush(krun);
}

// ============ kernel 5: EMA-w / embedding epilogue + loss finalize ============
__global__ __launch_bounds__(256)
void update_w_kernel(const float* __restrict__ ema_w, const float* __restrict__ dwacc,
                     const float* __restrict__ out_cs, const float* __restrict__ csum,
                     const float* __restrict__ lossbuf,
                     float* __restrict__ out_emb, float* __restrict__ out_emaw,
                     float* __restrict__ out_loss) {
    __shared__ float red[256];
    const int t = threadIdx.x;
    if (blockIdx.x == 0) {
        red[t] = lossbuf[t]; __syncthreads();
        #pragma unroll
        for (int off = 128; off > 0; off >>= 1) {
            if (t < off) red[t] += red[t + off];
            __syncthreads();
        }
        if (t == 0) out_loss[0] = 1.25f * red[0] / 8388608.0f;
    }

    const int g = blockIdx.x * 256 + t;          // float4 slot, 0..65535
    const int k = g >> 6;
    const float n_total = csum[0];
    const float cs = (out_cs[k] + EPS_F) / (n_total + 1024.0f * EPS_F) * n_total;

    const float4 w4 = *(const float4*)(ema_w + (size_t)g * 4);
    const float4 d4 = *(const float4*)(dwacc + (size_t)g * 4);
    float4 nw, ne;
    nw.x = DECAY_F * w4.x + OMD_F * d4.x;
    nw.y = DECAY_F * w4.y + OMD_F * d4.y;
    nw.z = DECAY_F * w4.z + OMD_F * d4.z;
    nw.w = DECAY_F * w4.w + OMD_F * d4.w;
    ne.x = nw.x / cs; ne.y = nw.y / cs; ne.z = nw.z / cs; ne.w = nw.w / cs;
    *(float4*)(out_emaw + (size_t)g * 4) = nw;
    *(float4*)(out_emb  + (size_t)g * 4) = ne;
}

// ======================= launcher =======================
extern "C" void kernel_launch(void* const* d_in, const int* in_sizes, int n_in,
                              void* d_out, int out_size, void* d_ws, size_t ws_size,
                              hipStream_t stream) {
    const float* z      = (const float*)d_in[0];
    const float* emb    = (const float*)d_in[1];
    const float* ema_cs = (const float*)d_in[2];
    const float* ema_w  = (const float*)d_in[3];

    float* out = (float*)d_out;
    char*  wsb = (char*)d_ws;

    int*            cnt     = (int*)(wsb + WSB_CNTI);
    float*          lossbuf = (float*)(wsb + WSB_LOSS);
    float*          dwacc   = (float*)(wsb + WSB_DWACC);
    float*          csum    = (float*)(wsb + WSB_CSUM);
    float*          enorm   = (float*)(wsb + WSB_ENORM);
    int*            idx     = (int*)(wsb + WSB_IDX);
    unsigned short* e_hi    = (unsigned short*)(wsb + WSB_EHI);
    unsigned short* e_lo    = (unsigned short*)(wsb + WSB_ELO);
    int*            sorted  = (int*)(wsb + WSB_SORT);
    int*            cursor  = (int*)(wsb + WSB_CURS);

    float* out_zq   = out + OUT_ZQ;
    float* out_loss = out + OUT_LOSS;
    float* out_idxf = out + OUT_IDX;
    float* out_emb  = out + OUT_EMB;
    float* out_cs   = out + OUT_CS;
    float* out_emaw = out + OUT_EMAW;

    esplit_enorm_kernel<<<256, 256, 0, stream>>>(emb, e_hi, e_lo, enorm,
                                                 dwacc, cnt, lossbuf);
    argmin_kernel<<<512, 256, 0, stream>>>(z, e_hi, e_lo, enorm, emb,
                                           idx, out_idxf, out_zq, cnt);
    scan_kernel<<<1, 1024, 0, stream>>>(ema_cs, cnt, out_cs, csum, cursor);
    scatter_kernel<<<128, 256, 0, stream>>>(idx, cursor, sorted);
    dw_kernel<<<512, 256, 0, stream>>>(z, emb, enorm, sorted, idx, dwacc, lossbuf);
    update_w_kernel<<<256, 256, 0, stream>>>(ema_w, dwacc, out_cs, csum, lossbuf,
                                             out_emb, out_emaw, out_loss);
}